// Round 1
// baseline (20.941 us; speedup 1.0000x reference)
//
#include <hip/hip_runtime.h>

#define B 4
#define CIN 64
#define H 32
#define W 32
#define KSZ 3
#define PADW 1
#define OC 64
#define LMAX 144
#define HP (H + 2*PADW)   // 34
#define WP (W + 2*PADW)   // 34
#define HOUT 32
#define WOUT 32
#define NPIX (HOUT*WOUT)  // 1024

// Kernel 1: zero-pad images into workspace.
// grid = B*CIN blocks, 256 threads; each block pads one (b,c) channel.
__global__ __launch_bounds__(256) void pad_kernel(const float* __restrict__ img,
                                                  float* __restrict__ padp) {
    int bc = blockIdx.x;                       // b*CIN + c
    const float* src = img + (size_t)bc * (H * W);
    float* dst = padp + (size_t)bc * (HP * WP);
    for (int p = threadIdx.x; p < HP * WP; p += 256) {
        int r = p / WP;
        int c = p - r * WP;
        int rr = r - PADW, cc = c - PADW;
        float v = 0.f;
        if ((unsigned)rr < (unsigned)H && (unsigned)cc < (unsigned)W)
            v = src[rr * W + cc];
        dst[p] = v;
    }
}

// Kernel 2: gather + weighted sum. One block per (b,o); one thread per pixel.
__global__ __launch_bounds__(1024) void gather_kernel(
    const float* __restrict__ padp,
    const int* __restrict__ tap_idx, const float* __restrict__ tap_w,
    const int* __restrict__ bias_index, const float* __restrict__ bias_value,
    float* __restrict__ out) {
    __shared__ int2 s_tap[LMAX];               // .x = tap offset, .y = weight bits
    int bo = blockIdx.x;
    int b = bo >> 6;                           // / OC
    int o = bo & (OC - 1);
    int t = threadIdx.x;
    if (t < LMAX) {
        int2 v;
        v.x = tap_idx[o * LMAX + t];
        v.y = __float_as_int(tap_w[o * LMAX + t]);
        s_tap[t] = v;
    }
    __syncthreads();

    // general scatter-add bias (bias_index may repeat in principle)
    float bias = 0.f;
    for (int i = 0; i < OC; ++i)
        bias += (bias_index[i] == o) ? bias_value[i] : 0.f;

    int h = t >> 5, w = t & 31;
    int pix = h * WP + w;                      // offset of this output pixel in padded image
    const float* base = padp + (size_t)b * (CIN * HP * WP) + pix;

    float acc = 0.f;
#pragma unroll 8
    for (int l = 0; l < LMAX; ++l) {
        int2 tp = s_tap[l];                    // broadcast ds_read_b64
        acc += __int_as_float(tp.y) * base[tp.x];
    }
    out[(size_t)bo * NPIX + t] = acc + bias;
}

// Fallback (workspace too small): decompose tap_idx, bounds-check per tap.
__global__ __launch_bounds__(1024) void gather_fallback(
    const float* __restrict__ img,
    const int* __restrict__ tap_idx, const float* __restrict__ tap_w,
    const int* __restrict__ bias_index, const float* __restrict__ bias_value,
    float* __restrict__ out) {
    __shared__ int4 s_tap[LMAX];               // x=rel offset, y=dr, z=dc, w=weight bits
    int bo = blockIdx.x;
    int b = bo >> 6;
    int o = bo & (OC - 1);
    int t = threadIdx.x;
    if (t < LMAX) {
        int idx = tap_idx[o * LMAX + t];
        int c = idx / (HP * WP);
        int rem = idx - c * (HP * WP);
        int kh = rem / WP;
        int kw = rem - kh * WP;
        int dr = kh - PADW, dc = kw - PADW;
        int4 v;
        v.x = c * (H * W) + dr * W + dc;
        v.y = dr;
        v.z = dc;
        v.w = __float_as_int(tap_w[o * LMAX + t]);
        s_tap[t] = v;
    }
    __syncthreads();

    float bias = 0.f;
    for (int i = 0; i < OC; ++i)
        bias += (bias_index[i] == o) ? bias_value[i] : 0.f;

    int h = t >> 5, w = t & 31;
    const float* base = img + (size_t)b * (CIN * H * W) + h * W + w;

    float acc = 0.f;
#pragma unroll 4
    for (int l = 0; l < LMAX; ++l) {
        int4 tp = s_tap[l];
        float v = 0.f;
        if ((unsigned)(h + tp.y) < (unsigned)H && (unsigned)(w + tp.z) < (unsigned)W)
            v = base[tp.x];                    // exec-masked load, no OOB on inactive lanes
        acc += __int_as_float(tp.w) * v;
    }
    out[(size_t)bo * NPIX + t] = acc + bias;
}

extern "C" void kernel_launch(void* const* d_in, const int* in_sizes, int n_in,
                              void* d_out, int out_size, void* d_ws, size_t ws_size,
                              hipStream_t stream) {
    const float* images     = (const float*)d_in[0];
    const int*   tap_idx    = (const int*)d_in[1];
    const float* tap_w      = (const float*)d_in[2];
    const int*   bias_index = (const int*)d_in[3];
    const float* bias_value = (const float*)d_in[4];
    float* out = (float*)d_out;

    size_t pad_bytes = (size_t)B * CIN * HP * WP * sizeof(float);
    if (ws_size >= pad_bytes) {
        float* padp = (float*)d_ws;
        pad_kernel<<<B * CIN, 256, 0, stream>>>(images, padp);
        gather_kernel<<<B * OC, 1024, 0, stream>>>(padp, tap_idx, tap_w,
                                                   bias_index, bias_value, out);
    } else {
        gather_fallback<<<B * OC, 1024, 0, stream>>>(images, tap_idx, tap_w,
                                                     bias_index, bias_value, out);
    }
}